// Round 6
// baseline (225.684 us; speedup 1.0000x reference)
//
#include <hip/hip_runtime.h>

// B=2, T=2048, C=1024, H=16, HD=64, SCALE=0.125
// Pipeline: cvt x->bf16; transpose W->bf16 [N][K]; GEMM1 qkv=x@Wqkv (bf16 out,
// Q cols pre-scaled by SCALE*log2e); transpose V part -> vT; flash attn v6
// (1 wave/block, 64 q-rows/wave as 4 subtiles sharing K/V register fragments,
// KVBLK=32, barrier-free self-paced gload_lds dbuf w/ counted vmcnt, swapped
// QK^T, O^T accum, exp2 softmax, cvt_pk, defer-max) -> att (bf16);
// GEMM2 out = att@Wp + bp (f32).

typedef __attribute__((ext_vector_type(8))) short shortx8;
typedef __attribute__((ext_vector_type(4))) short shortx4;
typedef __attribute__((ext_vector_type(8))) unsigned short ushortx8;
typedef __attribute__((ext_vector_type(4))) float f32x4;

#define MFMA16(a, b, c) __builtin_amdgcn_mfma_f32_16x16x32_bf16((a), (b), (c), 0, 0, 0)

// SCALE * log2(e): softmax done in exp2 domain; folded into Q at GEMM1 epilogue
#define SC_L2E 0.18033688011112042f

__device__ __forceinline__ unsigned short f2bf(float f) {
  union { float f; unsigned u; } v; v.f = f;
  unsigned r = v.u + 0x7fffu + ((v.u >> 16) & 1u);  // RNE; inputs finite
  return (unsigned short)(r >> 16);
}

__device__ __forceinline__ float fexp2(float x) {
#if __has_builtin(__builtin_amdgcn_exp2f)
  return __builtin_amdgcn_exp2f(x);
#else
  return exp2f(x);
#endif
}

__device__ __forceinline__ void gload16(const void* g, void* l) {
  __builtin_amdgcn_global_load_lds(
      (const __attribute__((address_space(1))) void*)g,
      (__attribute__((address_space(3))) void*)l, 16, 0, 0);
}

// ---------------- conversions ----------------
__global__ __launch_bounds__(256) void cvt_x(const float* __restrict__ x,
                                             unsigned short* __restrict__ xb, int n4) {
  int i = blockIdx.x * 256 + threadIdx.x;
  if (i < n4) {
    float4 v = ((const float4*)x)[i];
    unsigned short* o = xb + (size_t)i * 4;
    o[0] = f2bf(v.x); o[1] = f2bf(v.y); o[2] = f2bf(v.z); o[3] = f2bf(v.w);
  }
}

// 4x W [1024][1024] f32 -> WT [1024][1024] bf16 (WT[n][k] = W[k][n]); z picks matrix
__global__ __launch_bounds__(256) void transpose_w4(
    const float* __restrict__ Wq, const float* __restrict__ Wk,
    const float* __restrict__ Wv, const float* __restrict__ Wp,
    unsigned short* __restrict__ wqkvT, unsigned short* __restrict__ wpT) {
  __shared__ float tile[32][33];
  const int zi = blockIdx.z;
  const float* src = (zi == 0) ? Wq : (zi == 1) ? Wk : (zi == 2) ? Wv : Wp;
  unsigned short* dst = (zi == 3) ? wpT : wqkvT + (size_t)zi * 1048576;
  const int bx = blockIdx.x * 32, by = blockIdx.y * 32;
  const int tx = threadIdx.x & 31, ty = threadIdx.x >> 5;  // 32 x 8
  #pragma unroll
  for (int i = 0; i < 32; i += 8)
    tile[ty + i][tx] = src[(size_t)(by + ty + i) * 1024 + bx + tx];
  __syncthreads();
  #pragma unroll
  for (int i = 0; i < 32; i += 8)
    dst[(size_t)(bx + ty + i) * 1024 + by + tx] = f2bf(tile[tx][ty + i]);
}

// V part of qkv [4096][cols 2048..3071] bf16 -> vT [1024][4096] bf16
__global__ __launch_bounds__(256) void transpose_v(const unsigned short* __restrict__ qkv,
                                                   unsigned short* __restrict__ vT) {
  __shared__ unsigned short tile[64][65];
  const int bx = blockIdx.x * 64;  // hd dim (0..1023)
  const int by = blockIdx.y * 64;  // row dim (0..4095)
  const int t = threadIdx.x;
  const int r = t >> 3, c8 = (t & 7) << 3;
  #pragma unroll
  for (int i = 0; i < 2; ++i) {
    ushortx8 v = *(const ushortx8*)&qkv[(size_t)(by + i * 32 + r) * 3072 + 2048 + bx + c8];
    #pragma unroll
    for (int j = 0; j < 8; ++j) tile[i * 32 + r][c8 + j] = v[j];
  }
  __syncthreads();
  #pragma unroll
  for (int i = 0; i < 2; ++i) {
    const int dr = i * 32 + r;
    ushortx8 o;
    #pragma unroll
    for (int j = 0; j < 8; ++j) o[j] = tile[c8 + j][dr];
    *(ushortx8*)&vT[(size_t)(bx + dr) * 4096 + by + c8] = o;
  }
}

// ---------------- GEMM: C[M,N] = A[M,K] @ BT[N,K]^T ----------------
// qscale applied to bf16 output cols < scale_cols (folds attn scale into Q).
__global__ __launch_bounds__(256) void gemm_bt(
    const unsigned short* __restrict__ A, const unsigned short* __restrict__ BT,
    unsigned short* __restrict__ Cb, float* __restrict__ Cf,
    const float* __restrict__ bias, int M, int N, int K,
    float qscale, int scale_cols) {
  __shared__ unsigned short As[128 * 32];
  __shared__ unsigned short Bs[128 * 32];
  const int tid = threadIdx.x;
  const int lane = tid & 63, w = tid >> 6;
  const int wr = w >> 1, wc = w & 1;
  const int brow = blockIdx.y << 7, bcol = blockIdx.x << 7;

  f32x4 z = {0.f, 0.f, 0.f, 0.f};
  f32x4 acc[4][4];
  #pragma unroll
  for (int m = 0; m < 4; ++m)
    #pragma unroll
    for (int n = 0; n < 4; ++n) acc[m][n] = z;

  const int srow = tid >> 2;
  const int scol = (tid & 3) << 3;
  const unsigned short* Ap = A + (size_t)(brow + srow) * K + scol;
  const unsigned short* Bp = BT + (size_t)(bcol + srow) * K + scol;
  unsigned short* AsW = &As[w * 512];
  unsigned short* BsW = &Bs[w * 512];
  const size_t rowK64 = (size_t)64 * K;

  for (int k0 = 0; k0 < K; k0 += 32) {
    gload16(Ap + k0, AsW);
    gload16(Ap + rowK64 + k0, AsW + 2048);
    gload16(Bp + k0, BsW);
    gload16(Bp + rowK64 + k0, BsW + 2048);
    __syncthreads();
    shortx8 af[4], bf[4];
    const int koff = (lane >> 4) << 3;
    const int ar = (wr << 6) + (lane & 15);
    const int br = (wc << 6) + (lane & 15);
    #pragma unroll
    for (int m = 0; m < 4; ++m) af[m] = *(const shortx8*)&As[(ar + m * 16) * 32 + koff];
    #pragma unroll
    for (int n = 0; n < 4; ++n) bf[n] = *(const shortx8*)&Bs[(br + n * 16) * 32 + koff];
    #pragma unroll
    for (int m = 0; m < 4; ++m)
      #pragma unroll
      for (int n = 0; n < 4; ++n) acc[m][n] = MFMA16(af[m], bf[n], acc[m][n]);
    __syncthreads();
  }

  const int r0 = (lane >> 4) << 2;
  const int c0 = lane & 15;
  if (Cb) {
    #pragma unroll
    for (int m = 0; m < 4; ++m)
      #pragma unroll
      for (int n = 0; n < 4; ++n)
        #pragma unroll
        for (int j = 0; j < 4; ++j) {
          const size_t row = brow + (wr << 6) + m * 16 + r0 + j;
          const size_t col = bcol + (wc << 6) + n * 16 + c0;
          float v = acc[m][n][j];
          if ((int)col < scale_cols) v *= qscale;
          Cb[row * N + col] = f2bf(v);
        }
  } else {
    #pragma unroll
    for (int m = 0; m < 4; ++m)
      #pragma unroll
      for (int n = 0; n < 4; ++n)
        #pragma unroll
        for (int j = 0; j < 4; ++j) {
          const size_t row = brow + (wr << 6) + m * 16 + r0 + j;
          const size_t col = bcol + (wc << 6) + n * 16 + c0;
          Cf[row * N + col] = acc[m][n][j] + bias[col];
        }
  }
}

// ---------------- flash attention v6 ----------------
// 1 wave/block, 64 q-rows (4 subtiles of 16) sharing K/V register fragments.
// KVBLK=32. Barrier-free: wave stages its own K/V tiles via gload_lds dbuf,
// paced by counted vmcnt only. Swapped QK^T -> S^T (lane owns q-col ql,
// 2 shfl for max/sum). PV: O^T = mfma(V^T, P^T). Ps relayout: row-major
// [ql16][kv32] with XOR swizzle (2-way banks). K tile [32][64] / V^T tile
// [64][32] in LDS, read-side conflict-free via pre-swizzled global source.

__device__ __forceinline__ void softmax8_pack(
    const f32x4* sf, unsigned short* Ps, int ql, int g, int kv0, int qrow,
    bool msk, float& m_run, float& l_run) {
  float sv[8];
  #pragma unroll
  for (int f = 0; f < 2; ++f)
    #pragma unroll
    for (int j = 0; j < 4; ++j) {
      float v = sf[f][j];  // pre-scaled via Q
      if (msk && (kv0 + 16 * f + 4 * g + j > qrow)) v = -__builtin_inff();
      sv[f * 4 + j] = v;
    }
  float m4[4];
  #pragma unroll
  for (int i = 0; i < 4; ++i) m4[i] = fmaxf(sv[2 * i], sv[2 * i + 1]);
  float mx = fmaxf(fmaxf(m4[0], m4[1]), fmaxf(m4[2], m4[3]));
  mx = fmaxf(mx, __shfl_xor(mx, 16));
  mx = fmaxf(mx, __shfl_xor(mx, 32));

  float p[8];
  float nm = m_run;
  if (!__all(mx <= m_run + 8.0f)) nm = fmaxf(m_run, mx);  // defer-max (THR=8 log2)
  #pragma unroll
  for (int i = 0; i < 8; ++i) p[i] = fexp2(sv[i] - nm);
  float s4[4];
  #pragma unroll
  for (int i = 0; i < 4; ++i) s4[i] = p[2 * i] + p[2 * i + 1];
  float rsum = (s4[0] + s4[1]) + (s4[2] + s4[3]);
  rsum += __shfl_xor(rsum, 16);
  rsum += __shfl_xor(rsum, 32);
  if (nm != m_run) {
    const float alpha = fexp2(m_run - nm);
    l_run = l_run * alpha + rsum;
    m_run = nm;
    // caller rescales acc via returned alpha — instead fold here via flag:
    // (we keep alpha application at caller; see ALPHA_HACK below)
  } else {
    l_run += rsum;
  }

  // P^T -> Ps row-major [ql][kv] with XOR swizzle (bits 3..4 ^ (ql&3)<<3)
  const int X = (ql & 3) << 3;
  #pragma unroll
  for (int f = 0; f < 2; ++f) {
    unsigned lo, hi;
    asm("v_cvt_pk_bf16_f32 %0, %1, %2" : "=v"(lo) : "v"(p[4 * f + 0]), "v"(p[4 * f + 1]));
    asm("v_cvt_pk_bf16_f32 %0, %1, %2" : "=v"(hi) : "v"(p[4 * f + 2]), "v"(p[4 * f + 3]));
    uint2 uu; uu.x = lo; uu.y = hi;
    *(uint2*)&Ps[ql * 32 + ((16 * f + 4 * g) ^ X)] = uu;
  }
}

__global__ __launch_bounds__(64, 2) void attn_fwd(
    const unsigned short* __restrict__ qkv, const unsigned short* __restrict__ vT,
    unsigned short* __restrict__ att) {
  __shared__ unsigned short Ks[2][2048];  // [buf][32 kv][64 d]
  __shared__ unsigned short Vt[2][2048];  // [buf][64 d][32 kv]
  __shared__ unsigned short Ps[512];      // [16 ql][32 kv] XOR-swizzled

  const int lane = threadIdx.x;
  const int stream = blockIdx.x;  // consecutive blocks = different streams -> XCD affine
  const int h = stream & 15, b = stream >> 4;
  const int u = 31 - blockIdx.y;  // 64-row q-tile, descending work
  const int ql = lane & 15, g = lane >> 4;
  const int qmin = u * 64;

  // Q fragments (MFMA B-operand): Q[q=ql][d=32h2+8g+e]; pre-scaled by SC_L2E
  shortx8 qf[4][2];
  #pragma unroll
  for (int s = 0; s < 4; ++s) {
    const unsigned short* qp =
        qkv + ((size_t)(b * 2048 + qmin + 16 * s + ql)) * 3072 + h * 64 + (g << 3);
    qf[s][0] = *(const shortx8*)qp;
    qf[s][1] = *(const shortx8*)(qp + 32);
  }

  const f32x4 z = {0.f, 0.f, 0.f, 0.f};
  f32x4 acc[4][4];
  #pragma unroll
  for (int s = 0; s < 4; ++s)
    #pragma unroll
    for (int c = 0; c < 4; ++c) acc[s][c] = z;
  float m_run[4], l_run[4];
  #pragma unroll
  for (int s = 0; s < 4; ++s) { m_run[s] = -__builtin_inff(); l_run[s] = 0.f; }

  // staging source ptrs (pre-swizzled chunks; LDS dest linear)
  const int krow = lane >> 3;                                   // + 8i
  const int kch = ((lane & 7) ^ (krow & 7)) << 3;
  const unsigned short* kb =
      qkv + ((size_t)(b * 2048 + krow)) * 3072 + 1024 + h * 64 + kch;
  const int vrow = lane >> 2;                                   // + 16i
  const int vch = ((lane & 3) ^ ((lane >> 3) & 3)) << 3;
  const unsigned short* vb =
      vT + ((size_t)(h * 64 + vrow)) * 4096 + b * 2048 + vch;

  #define STAGE(kv0_, bufi_)                                              \
    do {                                                                  \
      _Pragma("unroll")                                                   \
      for (int i = 0; i < 4; ++i) {                                       \
        gload16(kb + (size_t)((kv0_) + 8 * i) * 3072, &Ks[bufi_][i * 512]); \
        gload16(vb + (size_t)(16 * i) * 4096 + (kv0_), &Vt[bufi_][i * 512]); \
      }                                                                   \
    } while (0)

  const int dmax = 2 * u + 1;
  int buf = 0;
  STAGE(0, 0);
  for (int d = 0; d <= dmax; ++d) {
    if (d < dmax) {
      STAGE((d + 1) * 32, buf ^ 1);
      asm volatile("s_waitcnt vmcnt(8)" ::: "memory");
    } else {
      asm volatile("s_waitcnt vmcnt(0)" ::: "memory");
    }
    __builtin_amdgcn_sched_barrier(0);
    const unsigned short* K = Ks[buf];
    const unsigned short* V = Vt[buf];
    const int kv0 = d * 32;

    // K fragments: [kv-group f][k-half h2], read once, reused by 4 subtiles
    shortx8 kf[2][2];
    #pragma unroll
    for (int f = 0; f < 2; ++f)
      #pragma unroll
      for (int h2 = 0; h2 < 2; ++h2)
        kf[f][h2] = *(const shortx8*)&K[(16 * f + ql) * 64 + (((4 * h2 + g) ^ (ql & 7)) << 3)];
    // V^T fragments: rows d=16c+ql, k=kv local 8g..8g+7 per lane
    shortx8 vf[4];
    #pragma unroll
    for (int c = 0; c < 4; ++c)
      vf[c] = *(const shortx8*)&V[(16 * c + ql) * 32 + ((g ^ ((ql >> 1) & 3)) << 3)];

    #pragma unroll
    for (int s = 0; s < 4; ++s) {
      const int qmin_s = qmin + 16 * s;
      if (kv0 > qmin_s + 15) continue;  // subtile inactive (wave-uniform)
      const bool msk = (kv0 + 31 > qmin_s);
      f32x4 sf[2];
      #pragma unroll
      for (int f = 0; f < 2; ++f) {
        f32x4 t = MFMA16(kf[f][0], qf[s][0], z);
        sf[f] = MFMA16(kf[f][1], qf[s][1], t);
      }
      const float m_old = m_run[s];
      softmax8_pack(sf, Ps, ql, g, kv0, qmin_s + ql, msk, m_run[s], l_run[s]);
      if (m_run[s] != m_old) {
        const float alpha = fexp2(m_old - m_run[s]);
        #pragma unroll
        for (int c = 0; c < 4; ++c) acc[s][c] *= alpha;
      }
      __builtin_amdgcn_sched_barrier(0);  // Ps write -> read order
      const shortx8 pf =
          *(const shortx8*)&Ps[ql * 32 + ((8 * g) ^ ((ql & 3) << 3))];
      __builtin_amdgcn_sched_barrier(0);
      #pragma unroll
      for (int c = 0; c < 4; ++c) acc[s][c] = MFMA16(vf[c], pf, acc[s][c]);
    }
    buf ^= 1;
  }
  #undef STAGE

  // epilogue: acc[s][c][j] = O^T[d=16c+4g+j][q=qmin+16s+ql]
  #pragma unroll
  for (int s = 0; s < 4; ++s) {
    const float inv = 1.f / l_run[s];
    unsigned short* o =
        att + ((size_t)(b * 2048 + qmin + 16 * s + ql)) * 1024 + h * 64 + 4 * g;
    #pragma unroll
    for (int c = 0; c < 4; ++c) {
      shortx4 a;
      #pragma unroll
      for (int j = 0; j < 4; ++j) a[j] = (short)f2bf(acc[s][c][j] * inv);
      *(shortx4*)&o[16 * c] = a;
    }
  }
}

// ---------------- launch ----------------
extern "C" void kernel_launch(void* const* d_in, const int* in_sizes, int n_in,
                              void* d_out, int out_size, void* d_ws, size_t ws_size,
                              hipStream_t stream) {
  const float* x  = (const float*)d_in[0];
  const float* Wq = (const float*)d_in[1];
  const float* Wk = (const float*)d_in[2];
  const float* Wv = (const float*)d_in[3];
  const float* Wp = (const float*)d_in[4];
  const float* bp = (const float*)d_in[5];

  char* ws = (char*)d_ws;
  unsigned short* xb    = (unsigned short*)(ws);                        //  8 MB [4096][1024]
  unsigned short* wqkvT = (unsigned short*)(ws + (size_t)8  * 1048576); //  6 MB [3072][1024]
  unsigned short* wpT   = (unsigned short*)(ws + (size_t)14 * 1048576); //  2 MB [1024][1024]
  unsigned short* qkv   = (unsigned short*)(ws + (size_t)16 * 1048576); // 24 MB [4096][3072]
  unsigned short* vT    = (unsigned short*)(ws + (size_t)40 * 1048576); //  8 MB [1024][4096]
  unsigned short* att   = (unsigned short*)(ws + (size_t)48 * 1048576); //  8 MB [4096][1024]

  cvt_x<<<dim3(4096), dim3(256), 0, stream>>>(x, xb, 1048576);
  transpose_w4<<<dim3(32, 32, 4), dim3(256), 0, stream>>>(Wq, Wk, Wv, Wp, wqkvT, wpT);
  gemm_bt<<<dim3(24, 32), dim3(256), 0, stream>>>(xb, wqkvT, qkv, nullptr, nullptr,
                                                  4096, 3072, 1024, SC_L2E, 1024);
  transpose_v<<<dim3(16, 64), dim3(256), 0, stream>>>(qkv, vT);
  attn_fwd<<<dim3(32, 32), dim3(64), 0, stream>>>(qkv, vT, att);
  gemm_bt<<<dim3(8, 32), dim3(256), 0, stream>>>(att, wpT, nullptr, (float*)d_out, bp,
                                                 4096, 1024, 1024, 0.f, 0);
}

// Round 7
// 138.644 us; speedup vs baseline: 1.6278x; 1.6278x over previous
//
#include <hip/hip_runtime.h>

// B=2, T=2048, C=1024, H=16, HD=64, SCALE=0.125
// Pipeline: cvt x->bf16; transpose W->bf16 [N][K]; GEMM1 qkv=x@Wqkv (bf16 out,
// Q cols pre-scaled by SCALE*log2e, V cols written transposed into vT);
// flash attn v7 (4 warps x 32 q-rows, swapped QK^T at 32x32x16 MFMA ->
// per-lane q column softmax w/ 1 shfl, in-register P relayout via
// cvt_pk + shfl_xor(32), O^T accum, dbuf K/V LDS + counted vmcnt) -> att;
// GEMM2 out = att@Wp + bp (f32).

typedef __attribute__((ext_vector_type(8))) short shortx8;
typedef __attribute__((ext_vector_type(4))) short shortx4;
typedef __attribute__((ext_vector_type(8))) unsigned short ushortx8;
typedef __attribute__((ext_vector_type(4))) float f32x4;
typedef __attribute__((ext_vector_type(16))) float f32x16;

#define MFMA16(a, b, c) __builtin_amdgcn_mfma_f32_16x16x32_bf16((a), (b), (c), 0, 0, 0)
#define MFMA32(a, b, c) __builtin_amdgcn_mfma_f32_32x32x16_bf16((a), (b), (c), 0, 0, 0)

// SCALE * log2(e): softmax done in exp2 domain; folded into Q at GEMM1 epilogue
#define SC_L2E 0.18033688011112042f

__device__ __forceinline__ unsigned short f2bf(float f) {
  union { float f; unsigned u; } v; v.f = f;
  unsigned r = v.u + 0x7fffu + ((v.u >> 16) & 1u);  // RNE; inputs finite
  return (unsigned short)(r >> 16);
}

__device__ __forceinline__ float fexp2(float x) {
#if __has_builtin(__builtin_amdgcn_exp2f)
  return __builtin_amdgcn_exp2f(x);
#else
  return exp2f(x);
#endif
}

__device__ __forceinline__ void gload16(const void* g, void* l) {
  __builtin_amdgcn_global_load_lds(
      (const __attribute__((address_space(1))) void*)g,
      (__attribute__((address_space(3))) void*)l, 16, 0, 0);
}

// ---------------- conversions ----------------
__global__ __launch_bounds__(256) void cvt_x(const float* __restrict__ x,
                                             unsigned short* __restrict__ xb, int n4) {
  int i = blockIdx.x * 256 + threadIdx.x;
  if (i < n4) {
    float4 v = ((const float4*)x)[i];
    unsigned short* o = xb + (size_t)i * 4;
    o[0] = f2bf(v.x); o[1] = f2bf(v.y); o[2] = f2bf(v.z); o[3] = f2bf(v.w);
  }
}

// 4x W [1024][1024] f32 -> WT [1024][1024] bf16 (WT[n][k] = W[k][n]); z picks matrix
__global__ __launch_bounds__(256) void transpose_w4(
    const float* __restrict__ Wq, const float* __restrict__ Wk,
    const float* __restrict__ Wv, const float* __restrict__ Wp,
    unsigned short* __restrict__ wqkvT, unsigned short* __restrict__ wpT) {
  __shared__ float tile[32][33];
  const int zi = blockIdx.z;
  const float* src = (zi == 0) ? Wq : (zi == 1) ? Wk : (zi == 2) ? Wv : Wp;
  unsigned short* dst = (zi == 3) ? wpT : wqkvT + (size_t)zi * 1048576;
  const int bx = blockIdx.x * 32, by = blockIdx.y * 32;
  const int tx = threadIdx.x & 31, ty = threadIdx.x >> 5;  // 32 x 8
  #pragma unroll
  for (int i = 0; i < 32; i += 8)
    tile[ty + i][tx] = src[(size_t)(by + ty + i) * 1024 + bx + tx];
  __syncthreads();
  #pragma unroll
  for (int i = 0; i < 32; i += 8)
    dst[(size_t)(bx + ty + i) * 1024 + by + tx] = f2bf(tile[tx][ty + i]);
}

// ---------------- GEMM: C[M,N] = A[M,K] @ BT[N,K]^T ----------------
// bf16 path: cols < scale_cols get qscale (Q prescale); cols >= 2048 (V part)
// are written TRANSPOSED into vTo[col-2048][row] when vTo != null.
__global__ __launch_bounds__(256) void gemm_bt(
    const unsigned short* __restrict__ A, const unsigned short* __restrict__ BT,
    unsigned short* __restrict__ Cb, float* __restrict__ Cf,
    const float* __restrict__ bias, int M, int N, int K,
    float qscale, int scale_cols, unsigned short* __restrict__ vTo) {
  __shared__ unsigned short As[128 * 32];
  __shared__ unsigned short Bs[128 * 32];
  const int tid = threadIdx.x;
  const int lane = tid & 63, w = tid >> 6;
  const int wr = w >> 1, wc = w & 1;
  const int brow = blockIdx.y << 7, bcol = blockIdx.x << 7;

  f32x4 z = {0.f, 0.f, 0.f, 0.f};
  f32x4 acc[4][4];
  #pragma unroll
  for (int m = 0; m < 4; ++m)
    #pragma unroll
    for (int n = 0; n < 4; ++n) acc[m][n] = z;

  const int srow = tid >> 2;
  const int scol = (tid & 3) << 3;
  const unsigned short* Ap = A + (size_t)(brow + srow) * K + scol;
  const unsigned short* Bp = BT + (size_t)(bcol + srow) * K + scol;
  unsigned short* AsW = &As[w * 512];
  unsigned short* BsW = &Bs[w * 512];
  const size_t rowK64 = (size_t)64 * K;

  for (int k0 = 0; k0 < K; k0 += 32) {
    gload16(Ap + k0, AsW);
    gload16(Ap + rowK64 + k0, AsW + 2048);
    gload16(Bp + k0, BsW);
    gload16(Bp + rowK64 + k0, BsW + 2048);
    __syncthreads();
    shortx8 af[4], bf[4];
    const int koff = (lane >> 4) << 3;
    const int ar = (wr << 6) + (lane & 15);
    const int br = (wc << 6) + (lane & 15);
    #pragma unroll
    for (int m = 0; m < 4; ++m) af[m] = *(const shortx8*)&As[(ar + m * 16) * 32 + koff];
    #pragma unroll
    for (int n = 0; n < 4; ++n) bf[n] = *(const shortx8*)&Bs[(br + n * 16) * 32 + koff];
    #pragma unroll
    for (int m = 0; m < 4; ++m)
      #pragma unroll
      for (int n = 0; n < 4; ++n) acc[m][n] = MFMA16(af[m], bf[n], acc[m][n]);
    __syncthreads();
  }

  const int r0 = (lane >> 4) << 2;
  const int c0 = lane & 15;
  if (Cb) {
    if (vTo && bcol >= 2048) {
      // V columns -> vT[d'][row], rows consecutive per lane -> 8B stores
      #pragma unroll
      for (int m = 0; m < 4; ++m)
        #pragma unroll
        for (int n = 0; n < 4; ++n) {
          const int dp = bcol - 2048 + (wc << 6) + n * 16 + c0;
          const size_t rowb = brow + (wr << 6) + m * 16 + r0;
          shortx4 o4;
          #pragma unroll
          for (int j = 0; j < 4; ++j) o4[j] = (short)f2bf(acc[m][n][j]);
          *(shortx4*)&vTo[(size_t)dp * 4096 + rowb] = o4;
        }
    } else {
      #pragma unroll
      for (int m = 0; m < 4; ++m)
        #pragma unroll
        for (int n = 0; n < 4; ++n)
          #pragma unroll
          for (int j = 0; j < 4; ++j) {
            const size_t row = brow + (wr << 6) + m * 16 + r0 + j;
            const size_t col = bcol + (wc << 6) + n * 16 + c0;
            float v = acc[m][n][j];
            if ((int)col < scale_cols) v *= qscale;
            Cb[row * N + col] = f2bf(v);
          }
    }
  } else {
    #pragma unroll
    for (int m = 0; m < 4; ++m)
      #pragma unroll
      for (int n = 0; n < 4; ++n)
        #pragma unroll
        for (int j = 0; j < 4; ++j) {
          const size_t row = brow + (wr << 6) + m * 16 + r0 + j;
          const size_t col = bcol + (wc << 6) + n * 16 + c0;
          Cf[row * N + col] = acc[m][n][j] + bias[col];
        }
  }
}

// ---------------- flash attention v7 (32x32 swapped MFMA) ----------------
// 4 warps/block, warp = 32 q rows (q = qb + 32*wid + (lane&31)). KVBLK=64.
// QK^T swapped: S^T[kv][q] = mfma32(A=K[32kv x 16k], B=Q^T[16k x 32q]) -> lane
// owns q-col (lane&31); its 32 regs + partner(lane^32) hold all 64 kv.
// Softmax fully per-lane: 31 fmax + 1 shfl. P -> PV B-operand in-register:
// 16 cvt_pk + 16 shfl_xor(32) + selects. PV: O^T = mfma32(A=V^T, B=P^T).
// K [64kv][64d] / V^T [64d][64kv] LDS tiles, source-pre-swizzled chunks,
// double-buffered, 2 barriers + counted vmcnt(4) per tile.

__global__ __launch_bounds__(256) void attn_fwd(
    const unsigned short* __restrict__ qkv, const unsigned short* __restrict__ vT,
    unsigned short* __restrict__ att) {
  __shared__ unsigned short Ks[2][4096];
  __shared__ unsigned short Vt[2][4096];

  const int tid = threadIdx.x;
  const int lane = tid & 63;
  const int wid = tid >> 6;
  const int stream = blockIdx.x;  // consecutive blocks = streams -> XCD affine
  const int h = stream & 15, b = stream >> 4;
  const int qt = 15 - (int)blockIdx.y;  // descending work
  const int ql = lane & 31;
  const int hi = lane >> 5;
  const int q = qt * 128 + 32 * wid + ql;
  const int swz = ql & 7;

  // Q^T B-operand: qf[kc] = Q[q][16kc + 8hi + e], pre-scaled by SC_L2E
  shortx8 qf[4];
  {
    const unsigned short* qp = qkv + ((size_t)(b * 2048 + q)) * 3072 + h * 64 + 8 * hi;
    #pragma unroll
    for (int kc = 0; kc < 4; ++kc) qf[kc] = *(const shortx8*)(qp + 16 * kc);
  }

  f32x16 z16;
  #pragma unroll
  for (int i = 0; i < 16; ++i) z16[i] = 0.f;
  f32x16 accO0 = z16, accO1 = z16;  // O^T[d = 32dh + crow(r,hi)][q]
  float m_run = -__builtin_inff(), l_run = 0.f;

  // staging: lane covers row 16*wid + 8j + (lane>>3), chunk (lane&7)^(row&7)
  const int srow0 = 16 * wid + ((lane >> 3) & 7);
  const int sch = ((tid & 7) ^ ((tid >> 3) & 7)) << 3;
  const unsigned short* kbp =
      qkv + ((size_t)(b * 2048 + srow0)) * 3072 + 1024 + h * 64 + sch;
  const unsigned short* vbp =
      vT + ((size_t)(h * 64 + srow0)) * 4096 + b * 2048 + sch;

  #define STAGE(kv0_, bufi_)                                                  \
    do {                                                                      \
      unsigned short* Kd = &Ks[bufi_][(16 * wid) * 64];                       \
      unsigned short* Vd = &Vt[bufi_][(16 * wid) * 64];                       \
      gload16(kbp + (size_t)(kv0_) * 3072, Kd);                               \
      gload16(kbp + (size_t)((kv0_) + 8) * 3072, Kd + 512);                   \
      gload16(vbp + (kv0_), Vd);                                              \
      gload16(vbp + (size_t)8 * 4096 + (kv0_), Vd + 512);                     \
    } while (0)

  const int tmax = 2 * qt + 1;
  const int tdiag = 2 * qt + (wid >> 1);
  int buf = 0;
  STAGE(0, 0);
  for (int t = 0; t <= tmax; ++t) {
    if (t < tmax) {
      STAGE((t + 1) * 64, buf ^ 1);
      asm volatile("s_waitcnt vmcnt(4)" ::: "memory");
    } else {
      asm volatile("s_waitcnt vmcnt(0)" ::: "memory");
    }
    __builtin_amdgcn_sched_barrier(0);
    __builtin_amdgcn_s_barrier();
    __builtin_amdgcn_sched_barrier(0);

    if (t <= tdiag) {
      const int kv0 = t * 64;
      const unsigned short* K = Ks[buf];
      const unsigned short* V = Vt[buf];

      // QK^T: s[c] = S^T chunk [32 kv (=32c+crow)][32 q]
      f32x16 s0 = z16, s1 = z16;
      #pragma unroll
      for (int kc = 0; kc < 4; ++kc) {
        shortx8 kf0 = *(const shortx8*)&K[ql * 64 + (((2 * kc + hi) ^ swz) << 3)];
        shortx8 kf1 = *(const shortx8*)&K[(32 + ql) * 64 + (((2 * kc + hi) ^ swz) << 3)];
        s0 = MFMA32(kf0, qf[kc], s0);
        s1 = MFMA32(kf1, qf[kc], s1);
      }

      // causal mask (diag tile only): kv_local = 32c + (r&3)+8*(r>>2)+4*hi
      if (t == tdiag) {
        const int qrel = q - kv0;
        #pragma unroll
        for (int r = 0; r < 16; ++r) {
          const int kvl = (r & 3) + 8 * (r >> 2) + 4 * hi;
          if (kvl > qrel) s0[r] = -__builtin_inff();
          if (kvl + 32 > qrel) s1[r] = -__builtin_inff();
        }
      }

      // per-lane max over 32 regs + 1 shfl across partner half
      float m16[16], m8[8], m4[4];
      #pragma unroll
      for (int r = 0; r < 16; ++r) m16[r] = fmaxf(s0[r], s1[r]);
      #pragma unroll
      for (int i = 0; i < 8; ++i) m8[i] = fmaxf(m16[2 * i], m16[2 * i + 1]);
      #pragma unroll
      for (int i = 0; i < 4; ++i) m4[i] = fmaxf(m8[2 * i], m8[2 * i + 1]);
      float mx = fmaxf(fmaxf(m4[0], m4[1]), fmaxf(m4[2], m4[3]));
      mx = fmaxf(mx, __shfl_xor(mx, 32));

      if (!__all(mx <= m_run + 8.0f)) {  // defer-max (THR=8 in log2)
        const float nm = fmaxf(m_run, mx);
        const float alpha = fexp2(m_run - nm);
        l_run *= alpha;
        #pragma unroll
        for (int r = 0; r < 16; ++r) { accO0[r] *= alpha; accO1[r] *= alpha; }
        m_run = nm;
      }

      // exponentiate in place
      #pragma unroll
      for (int r = 0; r < 16; ++r) {
        s0[r] = fexp2(s0[r] - m_run);
        s1[r] = fexp2(s1[r] - m_run);
      }
      // per-lane sum + 1 shfl
      float a8[8], a4[4];
      #pragma unroll
      for (int r = 0; r < 8; ++r) a8[r] = (s0[2 * r] + s0[2 * r + 1]) + (s1[2 * r] + s1[2 * r + 1]);
      #pragma unroll
      for (int i = 0; i < 4; ++i) a4[i] = a8[2 * i] + a8[2 * i + 1];
      float rsum = (a4[0] + a4[1]) + (a4[2] + a4[3]);
      rsum += __shfl_xor(rsum, 32);
      l_run += rsum;

      // pack P + in-register exchange + PV, per 32-kv chunk c
      #pragma unroll
      for (int c = 0; c < 2; ++c) {
        unsigned wv[8], xv[8];
        #pragma unroll
        for (int i = 0; i < 8; ++i) {
          float lo = (c == 0) ? s0[2 * i] : s1[2 * i];
          float hi2 = (c == 0) ? s0[2 * i + 1] : s1[2 * i + 1];
          asm("v_cvt_pk_bf16_f32 %0, %1, %2" : "=v"(wv[i]) : "v"(lo), "v"(hi2));
        }
        #pragma unroll
        for (int i = 0; i < 8; ++i) xv[i] = __shfl_xor(wv[i], 32);
        #pragma unroll
        for (int ss = 0; ss < 2; ++ss) {  // ks = 2c + ss
          union { unsigned u[4]; shortx8 s8; } pb;
          pb.u[0] = hi ? xv[4 * ss + 2] : wv[4 * ss];
          pb.u[1] = hi ? xv[4 * ss + 3] : wv[4 * ss + 1];
          pb.u[2] = hi ? wv[4 * ss + 2] : xv[4 * ss];
          pb.u[3] = hi ? wv[4 * ss + 3] : xv[4 * ss + 1];
          const int ks = 2 * c + ss;
          shortx8 va0 = *(const shortx8*)&V[ql * 64 + (((2 * ks + hi) ^ swz) << 3)];
          shortx8 va1 = *(const shortx8*)&V[(32 + ql) * 64 + (((2 * ks + hi) ^ swz) << 3)];
          accO0 = MFMA32(va0, pb.s8, accO0);
          accO1 = MFMA32(va1, pb.s8, accO1);
        }
      }
    }

    __builtin_amdgcn_sched_barrier(0);
    __builtin_amdgcn_s_barrier();
    __builtin_amdgcn_sched_barrier(0);
    buf ^= 1;
  }
  #undef STAGE

  // epilogue: accO{dh}[r] = O^T[d = 32dh + (r&3)+8(r>>2)+4hi][q]
  const float inv = 1.f / l_run;
  unsigned short* op = att + ((size_t)(b * 2048 + q)) * 1024 + h * 64;
  #pragma unroll
  for (int rq = 0; rq < 4; ++rq) {
    shortx4 o0, o1;
    #pragma unroll
    for (int j = 0; j < 4; ++j) {
      o0[j] = (short)f2bf(accO0[4 * rq + j] * inv);
      o1[j] = (short)f2bf(accO1[4 * rq + j] * inv);
    }
    *(shortx4*)&op[8 * rq + 4 * hi] = o0;
    *(shortx4*)&op[32 + 8 * rq + 4 * hi] = o1;
  }
}

// ---------------- launch ----------------
extern "C" void kernel_launch(void* const* d_in, const int* in_sizes, int n_in,
                              void* d_out, int out_size, void* d_ws, size_t ws_size,
                              hipStream_t stream) {
  const float* x  = (const float*)d_in[0];
  const float* Wq = (const float*)d_in[1];
  const float* Wk = (const float*)d_in[2];
  const float* Wv = (const float*)d_in[3];
  const float* Wp = (const float*)d_in[4];
  const float* bp = (const float*)d_in[5];

  char* ws = (char*)d_ws;
  unsigned short* xb    = (unsigned short*)(ws);                        //  8 MB [4096][1024]
  unsigned short* wqkvT = (unsigned short*)(ws + (size_t)8  * 1048576); //  6 MB [3072][1024]
  unsigned short* wpT   = (unsigned short*)(ws + (size_t)14 * 1048576); //  2 MB [1024][1024]
  unsigned short* qkv   = (unsigned short*)(ws + (size_t)16 * 1048576); // 24 MB [4096][3072]
  unsigned short* vT    = (unsigned short*)(ws + (size_t)40 * 1048576); //  8 MB [1024][4096]
  unsigned short* att   = (unsigned short*)(ws + (size_t)48 * 1048576); //  8 MB [4096][1024]

  cvt_x<<<dim3(4096), dim3(256), 0, stream>>>(x, xb, 1048576);
  transpose_w4<<<dim3(32, 32, 4), dim3(256), 0, stream>>>(Wq, Wk, Wv, Wp, wqkvT, wpT);
  gemm_bt<<<dim3(24, 32), dim3(256), 0, stream>>>(xb, wqkvT, qkv, nullptr, nullptr,
                                                  4096, 3072, 1024, SC_L2E, 1024, vT);
  attn_fwd<<<dim3(32, 16), dim3(256), 0, stream>>>(qkv, vT, att);
  gemm_bt<<<dim3(8, 32), dim3(256), 0, stream>>>(att, wpT, nullptr, (float*)d_out, bp,
                                                 4096, 1024, 1024, 0.f, 0, nullptr);
}

// Round 8
// 129.889 us; speedup vs baseline: 1.7375x; 1.0674x over previous
//
#include <hip/hip_runtime.h>

// B=2, T=2048, C=1024, H=16, HD=64, SCALE=0.125
// Pipeline: cvt x->bf16; transpose W->bf16 [N][K]; GEMM1 qkv=x@Wqkv (bf16 out,
// Q cols pre-scaled by SCALE*log2e, V cols written transposed into vT);
// flash attn v8 (2 independent warps/block over same 32 q-rows, kv-parity
// split, KVBLK=32, barrier-free self-paced gload_lds dbuf + counted vmcnt,
// swapped 32x32 QK^T, in-register P relayout, O^T accum, end merge via LDS)
// -> att; GEMM2 out = att@Wp + bp (f32).

typedef __attribute__((ext_vector_type(8))) short shortx8;
typedef __attribute__((ext_vector_type(4))) short shortx4;
typedef __attribute__((ext_vector_type(8))) unsigned short ushortx8;
typedef __attribute__((ext_vector_type(4))) float f32x4;
typedef __attribute__((ext_vector_type(16))) float f32x16;

#define MFMA16(a, b, c) __builtin_amdgcn_mfma_f32_16x16x32_bf16((a), (b), (c), 0, 0, 0)
#define MFMA32(a, b, c) __builtin_amdgcn_mfma_f32_32x32x16_bf16((a), (b), (c), 0, 0, 0)

// SCALE * log2(e): softmax done in exp2 domain; folded into Q at GEMM1 epilogue
#define SC_L2E 0.18033688011112042f

__device__ __forceinline__ unsigned short f2bf(float f) {
  union { float f; unsigned u; } v; v.f = f;
  unsigned r = v.u + 0x7fffu + ((v.u >> 16) & 1u);  // RNE; inputs finite
  return (unsigned short)(r >> 16);
}

__device__ __forceinline__ float fexp2(float x) {
#if __has_builtin(__builtin_amdgcn_exp2f)
  return __builtin_amdgcn_exp2f(x);
#else
  return exp2f(x);
#endif
}

__device__ __forceinline__ void gload16(const void* g, void* l) {
  __builtin_amdgcn_global_load_lds(
      (const __attribute__((address_space(1))) void*)g,
      (__attribute__((address_space(3))) void*)l, 16, 0, 0);
}

// ---------------- conversions ----------------
__global__ __launch_bounds__(256) void cvt_x(const float* __restrict__ x,
                                             unsigned short* __restrict__ xb, int n4) {
  int i = blockIdx.x * 256 + threadIdx.x;
  if (i < n4) {
    float4 v = ((const float4*)x)[i];
    unsigned short* o = xb + (size_t)i * 4;
    o[0] = f2bf(v.x); o[1] = f2bf(v.y); o[2] = f2bf(v.z); o[3] = f2bf(v.w);
  }
}

// 4x W [1024][1024] f32 -> WT [1024][1024] bf16 (WT[n][k] = W[k][n]); z picks matrix
__global__ __launch_bounds__(256) void transpose_w4(
    const float* __restrict__ Wq, const float* __restrict__ Wk,
    const float* __restrict__ Wv, const float* __restrict__ Wp,
    unsigned short* __restrict__ wqkvT, unsigned short* __restrict__ wpT) {
  __shared__ float tile[32][33];
  const int zi = blockIdx.z;
  const float* src = (zi == 0) ? Wq : (zi == 1) ? Wk : (zi == 2) ? Wv : Wp;
  unsigned short* dst = (zi == 3) ? wpT : wqkvT + (size_t)zi * 1048576;
  const int bx = blockIdx.x * 32, by = blockIdx.y * 32;
  const int tx = threadIdx.x & 31, ty = threadIdx.x >> 5;  // 32 x 8
  #pragma unroll
  for (int i = 0; i < 32; i += 8)
    tile[ty + i][tx] = src[(size_t)(by + ty + i) * 1024 + bx + tx];
  __syncthreads();
  #pragma unroll
  for (int i = 0; i < 32; i += 8)
    dst[(size_t)(bx + ty + i) * 1024 + by + tx] = f2bf(tile[tx][ty + i]);
}

// ---------------- GEMM: C[M,N] = A[M,K] @ BT[N,K]^T ----------------
// bf16 path: cols < scale_cols get qscale (Q prescale); cols >= 2048 (V part)
// are written TRANSPOSED into vTo[col-2048][row] when vTo != null.
__global__ __launch_bounds__(256) void gemm_bt(
    const unsigned short* __restrict__ A, const unsigned short* __restrict__ BT,
    unsigned short* __restrict__ Cb, float* __restrict__ Cf,
    const float* __restrict__ bias, int M, int N, int K,
    float qscale, int scale_cols, unsigned short* __restrict__ vTo) {
  __shared__ unsigned short As[128 * 32];
  __shared__ unsigned short Bs[128 * 32];
  const int tid = threadIdx.x;
  const int lane = tid & 63, w = tid >> 6;
  const int wr = w >> 1, wc = w & 1;
  const int brow = blockIdx.y << 7, bcol = blockIdx.x << 7;

  f32x4 z = {0.f, 0.f, 0.f, 0.f};
  f32x4 acc[4][4];
  #pragma unroll
  for (int m = 0; m < 4; ++m)
    #pragma unroll
    for (int n = 0; n < 4; ++n) acc[m][n] = z;

  const int srow = tid >> 2;
  const int scol = (tid & 3) << 3;
  const unsigned short* Ap = A + (size_t)(brow + srow) * K + scol;
  const unsigned short* Bp = BT + (size_t)(bcol + srow) * K + scol;
  unsigned short* AsW = &As[w * 512];
  unsigned short* BsW = &Bs[w * 512];
  const size_t rowK64 = (size_t)64 * K;

  for (int k0 = 0; k0 < K; k0 += 32) {
    gload16(Ap + k0, AsW);
    gload16(Ap + rowK64 + k0, AsW + 2048);
    gload16(Bp + k0, BsW);
    gload16(Bp + rowK64 + k0, BsW + 2048);
    __syncthreads();
    shortx8 af[4], bf[4];
    const int koff = (lane >> 4) << 3;
    const int ar = (wr << 6) + (lane & 15);
    const int br = (wc << 6) + (lane & 15);
    #pragma unroll
    for (int m = 0; m < 4; ++m) af[m] = *(const shortx8*)&As[(ar + m * 16) * 32 + koff];
    #pragma unroll
    for (int n = 0; n < 4; ++n) bf[n] = *(const shortx8*)&Bs[(br + n * 16) * 32 + koff];
    #pragma unroll
    for (int m = 0; m < 4; ++m)
      #pragma unroll
      for (int n = 0; n < 4; ++n) acc[m][n] = MFMA16(af[m], bf[n], acc[m][n]);
    __syncthreads();
  }

  const int r0 = (lane >> 4) << 2;
  const int c0 = lane & 15;
  if (Cb) {
    if (vTo && bcol >= 2048) {
      #pragma unroll
      for (int m = 0; m < 4; ++m)
        #pragma unroll
        for (int n = 0; n < 4; ++n) {
          const int dp = bcol - 2048 + (wc << 6) + n * 16 + c0;
          const size_t rowb = brow + (wr << 6) + m * 16 + r0;
          shortx4 o4;
          #pragma unroll
          for (int j = 0; j < 4; ++j) o4[j] = (short)f2bf(acc[m][n][j]);
          *(shortx4*)&vTo[(size_t)dp * 4096 + rowb] = o4;
        }
    } else {
      #pragma unroll
      for (int m = 0; m < 4; ++m)
        #pragma unroll
        for (int n = 0; n < 4; ++n)
          #pragma unroll
          for (int j = 0; j < 4; ++j) {
            const size_t row = brow + (wr << 6) + m * 16 + r0 + j;
            const size_t col = bcol + (wc << 6) + n * 16 + c0;
            float v = acc[m][n][j];
            if ((int)col < scale_cols) v *= qscale;
            Cb[row * N + col] = f2bf(v);
          }
    }
  } else {
    #pragma unroll
    for (int m = 0; m < 4; ++m)
      #pragma unroll
      for (int n = 0; n < 4; ++n)
        #pragma unroll
        for (int j = 0; j < 4; ++j) {
          const size_t row = brow + (wr << 6) + m * 16 + r0 + j;
          const size_t col = bcol + (wc << 6) + n * 16 + c0;
          Cf[row * N + col] = acc[m][n][j] + bias[col];
        }
  }
}

// ---------------- flash attention v8 (kv-split, barrier-free) ----------------
// Block = 2 INDEPENDENT warps over the same 32 q-rows; warp p does kv tiles
// t === p (mod 2), KVBLK=32. Each warp self-stages its K [32kv][64d] and
// V^T [64d][32kv] tiles (own dbuf, 8 gload16/tile, counted vmcnt(8)).
// QK^T swapped at 32x32x16: lane owns q-col ql; softmax per-lane (15 fmax +
// 1 shfl). P relayout in-register (8 cvt_pk + 8 shfl_xor(32)). O^T accum.
// End: warp1 dumps (m,l,O) to LDS; warp0 merges + stores. 2 barriers total.

__global__ __launch_bounds__(128, 4) void attn_fwd(
    const unsigned short* __restrict__ qkv, const unsigned short* __restrict__ vT,
    unsigned short* __restrict__ att) {
  __shared__ unsigned short Ks[2][2][2048];  // [warp][buf][32 kv][64 d]
  __shared__ unsigned short Vt[2][2][2048];  // [warp][buf][64 d][32 kv]

  const int tid = threadIdx.x;
  const int lane = tid & 63;
  const int p = tid >> 6;                  // warp id = kv parity
  const int stream = blockIdx.x;           // (h,b)
  const int h = stream & 15, b = stream >> 4;
  const int qb = 63 - (int)blockIdx.y;     // 32-row q tile, descending work
  const int ql = lane & 31;
  const int hi = lane >> 5;
  const int q = qb * 32 + ql;

  // Q^T B-operand: qf[kc] = Q[q][16kc + 8hi + e], pre-scaled by SC_L2E
  shortx8 qf[4];
  {
    const unsigned short* qp = qkv + ((size_t)(b * 2048 + q)) * 3072 + h * 64 + 8 * hi;
    #pragma unroll
    for (int kc = 0; kc < 4; ++kc) qf[kc] = *(const shortx8*)(qp + 16 * kc);
  }

  f32x16 z16;
  #pragma unroll
  for (int i = 0; i < 16; ++i) z16[i] = 0.f;
  f32x16 accO0 = z16, accO1 = z16;  // O^T[d = 32dh + crow(r,hi)][q]
  float m_run = -__builtin_inff(), l_run = 0.f;

  // staging source bases (pre-swizzled): K row r -> chunk XOR S8(r), V -> S4(r)
  const unsigned short* kb[4];
  const unsigned short* vb[4];
  #pragma unroll
  for (int i = 0; i < 4; ++i) {
    const int krow = 8 * i + (lane >> 3);
    const int kcl = (lane & 7) ^ (((krow >> 1) ^ (krow >> 4)) & 7);
    kb[i] = qkv + ((size_t)(b * 2048 + krow)) * 3072 + 1024 + h * 64 + 8 * kcl;
    const int vrow = 16 * i + (lane >> 2);
    const int vcl = (lane & 3) ^ (((vrow >> 1) ^ (vrow >> 3)) & 3);
    vb[i] = vT + ((size_t)(h * 64 + vrow)) * 4096 + b * 2048 + 8 * vcl;
  }
  const int rs8 = ((ql >> 1) ^ (ql >> 4)) & 7;
  const int rs4 = ((ql >> 1) ^ (ql >> 3)) & 3;

  #define STAGE(t_, bi_)                                                    \
    do {                                                                    \
      _Pragma("unroll")                                                     \
      for (int i = 0; i < 4; ++i) {                                         \
        gload16(kb[i] + (size_t)(t_) * 32 * 3072, &Ks[p][bi_][i * 512]);    \
        gload16(vb[i] + (t_) * 32, &Vt[p][bi_][i * 512]);                   \
      }                                                                     \
    } while (0)

  int buf = 0;
  if (p <= qb) STAGE(p, 0);
  for (int t = p; t <= qb; t += 2) {
    if (t + 2 <= qb) {
      STAGE(t + 2, buf ^ 1);
      asm volatile("s_waitcnt vmcnt(8)" ::: "memory");
    } else {
      asm volatile("s_waitcnt vmcnt(0)" ::: "memory");
    }
    __builtin_amdgcn_sched_barrier(0);
    const unsigned short* K = &Ks[p][buf][0];
    const unsigned short* V = &Vt[p][buf][0];

    // QK^T: s = S^T[32kv][32q]
    shortx8 kf[4];
    #pragma unroll
    for (int kc = 0; kc < 4; ++kc)
      kf[kc] = *(const shortx8*)&K[ql * 64 + 8 * ((2 * kc + hi) ^ rs8)];
    __builtin_amdgcn_s_setprio(1);
    f32x16 s = z16;
    #pragma unroll
    for (int kc = 0; kc < 4; ++kc) s = MFMA32(kf[kc], qf[kc], s);
    __builtin_amdgcn_s_setprio(0);

    // V^T fragments early (latency hides under softmax)
    shortx8 vf[2][2];
    #pragma unroll
    for (int dh = 0; dh < 2; ++dh)
      #pragma unroll
      for (int ks = 0; ks < 2; ++ks)
        vf[dh][ks] = *(const shortx8*)&V[(32 * dh + ql) * 32 + 8 * ((2 * ks + hi) ^ rs4)];

    // causal mask on diagonal tile: kv_local = (r&3)+8(r>>2)+4hi, qrel = ql
    if (t == qb) {
      #pragma unroll
      for (int r = 0; r < 16; ++r) {
        const int kvl = (r & 3) + 8 * (r >> 2) + 4 * hi;
        if (kvl > ql) s[r] = -__builtin_inff();
      }
    }

    // per-lane softmax over 16 regs + partner shfl
    float m8[8], m4[4];
    #pragma unroll
    for (int i = 0; i < 8; ++i) m8[i] = fmaxf(s[2 * i], s[2 * i + 1]);
    #pragma unroll
    for (int i = 0; i < 4; ++i) m4[i] = fmaxf(m8[2 * i], m8[2 * i + 1]);
    float mx = fmaxf(fmaxf(m4[0], m4[1]), fmaxf(m4[2], m4[3]));
    mx = fmaxf(mx, __shfl_xor(mx, 32));

    if (!__all(mx <= m_run + 8.0f)) {  // defer-max (THR=8 in log2)
      const float nm = fmaxf(m_run, mx);
      const float alpha = fexp2(m_run - nm);
      l_run *= alpha;
      #pragma unroll
      for (int r = 0; r < 16; ++r) { accO0[r] *= alpha; accO1[r] *= alpha; }
      m_run = nm;
    }

    #pragma unroll
    for (int r = 0; r < 16; ++r) s[r] = fexp2(s[r] - m_run);
    float a8[8], a4[4];
    #pragma unroll
    for (int i = 0; i < 8; ++i) a8[i] = s[2 * i] + s[2 * i + 1];
    #pragma unroll
    for (int i = 0; i < 4; ++i) a4[i] = a8[2 * i] + a8[2 * i + 1];
    float rsum = (a4[0] + a4[1]) + (a4[2] + a4[3]);
    rsum += __shfl_xor(rsum, 32);
    l_run += rsum;

    // pack P + in-register exchange + PV
    unsigned wv[8], xv[8];
    #pragma unroll
    for (int i = 0; i < 8; ++i)
      asm("v_cvt_pk_bf16_f32 %0, %1, %2" : "=v"(wv[i]) : "v"(s[2 * i]), "v"(s[2 * i + 1]));
    #pragma unroll
    for (int i = 0; i < 8; ++i) xv[i] = __shfl_xor(wv[i], 32);
    __builtin_amdgcn_s_setprio(1);
    #pragma unroll
    for (int ss = 0; ss < 2; ++ss) {
      union { unsigned u[4]; shortx8 s8; } pb;
      pb.u[0] = hi ? xv[4 * ss + 2] : wv[4 * ss];
      pb.u[1] = hi ? xv[4 * ss + 3] : wv[4 * ss + 1];
      pb.u[2] = hi ? wv[4 * ss + 2] : xv[4 * ss];
      pb.u[3] = hi ? wv[4 * ss + 3] : xv[4 * ss + 1];
      accO0 = MFMA32(vf[0][ss], pb.s8, accO0);
      accO1 = MFMA32(vf[1][ss], pb.s8, accO1);
    }
    __builtin_amdgcn_s_setprio(0);
    buf ^= 1;
  }
  #undef STAGE

  // ---- merge the two kv-partial states ----
  __syncthreads();
  float* mb = (float*)&Ks[0][0][0];  // 8 KB: [reg-group 8][lane 64][4 f32]
  float* ml = (float*)&Vt[0][0][0];  // 512 B: m[64], l[64]
  if (p == 1) {
    #pragma unroll
    for (int rg = 0; rg < 4; ++rg) {
      f32x4 v0 = {accO0[4 * rg], accO0[4 * rg + 1], accO0[4 * rg + 2], accO0[4 * rg + 3]};
      f32x4 v1 = {accO1[4 * rg], accO1[4 * rg + 1], accO1[4 * rg + 2], accO1[4 * rg + 3]};
      *(f32x4*)&mb[(rg * 64 + lane) * 4] = v0;
      *(f32x4*)&mb[((4 + rg) * 64 + lane) * 4] = v1;
    }
    ml[lane] = m_run;
    ml[64 + lane] = l_run;
  }
  __syncthreads();
  if (p == 0) {
    const float m1 = ml[lane], l1 = ml[64 + lane];
    const float mf = fmaxf(m_run, m1);
    const float a0 = fexp2(m_run - mf);
    const float a1 = fexp2(m1 - mf);
    const float inv = 1.f / (l_run * a0 + l1 * a1);
    unsigned short* op = att + ((size_t)(b * 2048 + q)) * 1024 + h * 64;
    #pragma unroll
    for (int rq = 0; rq < 4; ++rq) {
      f32x4 p0 = *(const f32x4*)&mb[(rq * 64 + lane) * 4];
      f32x4 p1 = *(const f32x4*)&mb[((4 + rq) * 64 + lane) * 4];
      shortx4 o0, o1;
      #pragma unroll
      for (int j = 0; j < 4; ++j) {
        o0[j] = (short)f2bf((accO0[4 * rq + j] * a0 + p0[j] * a1) * inv);
        o1[j] = (short)f2bf((accO1[4 * rq + j] * a0 + p1[j] * a1) * inv);
      }
      *(shortx4*)&op[8 * rq + 4 * hi] = o0;
      *(shortx4*)&op[32 + 8 * rq + 4 * hi] = o1;
    }
  }
}

// ---------------- launch ----------------
extern "C" void kernel_launch(void* const* d_in, const int* in_sizes, int n_in,
                              void* d_out, int out_size, void* d_ws, size_t ws_size,
                              hipStream_t stream) {
  const float* x  = (const float*)d_in[0];
  const float* Wq = (const float*)d_in[1];
  const float* Wk = (const float*)d_in[2];
  const float* Wv = (const float*)d_in[3];
  const float* Wp = (const float*)d_in[4];
  const float* bp = (const float*)d_in[5];

  char* ws = (char*)d_ws;
  unsigned short* xb    = (unsigned short*)(ws);                        //  8 MB [4096][1024]
  unsigned short* wqkvT = (unsigned short*)(ws + (size_t)8  * 1048576); //  6 MB [3072][1024]
  unsigned short* wpT   = (unsigned short*)(ws + (size_t)14 * 1048576); //  2 MB [1024][1024]
  unsigned short* qkv   = (unsigned short*)(ws + (size_t)16 * 1048576); // 24 MB [4096][3072]
  unsigned short* vT    = (unsigned short*)(ws + (size_t)40 * 1048576); //  8 MB [1024][4096]
  unsigned short* att   = (unsigned short*)(ws + (size_t)48 * 1048576); //  8 MB [4096][1024]

  cvt_x<<<dim3(4096), dim3(256), 0, stream>>>(x, xb, 1048576);
  transpose_w4<<<dim3(32, 32, 4), dim3(256), 0, stream>>>(Wq, Wk, Wv, Wp, wqkvT, wpT);
  gemm_bt<<<dim3(24, 32), dim3(256), 0, stream>>>(xb, wqkvT, qkv, nullptr, nullptr,
                                                  4096, 3072, 1024, SC_L2E, 1024, vT);
  attn_fwd<<<dim3(32, 64), dim3(128), 0, stream>>>(qkv, vT, att);
  gemm_bt<<<dim3(8, 32), dim3(256), 0, stream>>>(att, wpT, nullptr, (float*)d_out, bp,
                                                 4096, 1024, 1024, 0.f, 0, nullptr);
}

// Round 9
// 124.761 us; speedup vs baseline: 1.8089x; 1.0411x over previous
//
#include <hip/hip_runtime.h>

// B=2, T=2048, C=1024, H=16, HD=64, SCALE=0.125
// Pipeline: cvt x->bf16; transpose W->bf16 [N][K]; GEMM1 qkv=x@Wqkv (bf16 out,
// Q cols pre-scaled by SCALE*log2e, V cols written transposed into vT);
// flash attn v9 (2 independent warps/block over same 32 q-rows, kv-parity
// split, KVBLK=32, SINGLE 8KB LDS buffer per warp: vmcnt(0) -> ds_read all
// frags -> lgkmcnt(0) -> restage same buffer; swapped 32x32 QK^T, in-register
// P relayout, O^T accum, end merge via LDS) -> att; GEMM2 out = att@Wp + bp.

typedef __attribute__((ext_vector_type(8))) short shortx8;
typedef __attribute__((ext_vector_type(4))) short shortx4;
typedef __attribute__((ext_vector_type(8))) unsigned short ushortx8;
typedef __attribute__((ext_vector_type(4))) float f32x4;
typedef __attribute__((ext_vector_type(16))) float f32x16;

#define MFMA16(a, b, c) __builtin_amdgcn_mfma_f32_16x16x32_bf16((a), (b), (c), 0, 0, 0)
#define MFMA32(a, b, c) __builtin_amdgcn_mfma_f32_32x32x16_bf16((a), (b), (c), 0, 0, 0)

// SCALE * log2(e): softmax done in exp2 domain; folded into Q at GEMM1 epilogue
#define SC_L2E 0.18033688011112042f

__device__ __forceinline__ unsigned short f2bf(float f) {
  union { float f; unsigned u; } v; v.f = f;
  unsigned r = v.u + 0x7fffu + ((v.u >> 16) & 1u);  // RNE; inputs finite
  return (unsigned short)(r >> 16);
}

__device__ __forceinline__ float fexp2(float x) {
#if __has_builtin(__builtin_amdgcn_exp2f)
  return __builtin_amdgcn_exp2f(x);
#else
  return exp2f(x);
#endif
}

__device__ __forceinline__ void gload16(const void* g, void* l) {
  __builtin_amdgcn_global_load_lds(
      (const __attribute__((address_space(1))) void*)g,
      (__attribute__((address_space(3))) void*)l, 16, 0, 0);
}

// ---------------- conversions ----------------
__global__ __launch_bounds__(256) void cvt_x(const float* __restrict__ x,
                                             unsigned short* __restrict__ xb, int n4) {
  int i = blockIdx.x * 256 + threadIdx.x;
  if (i < n4) {
    float4 v = ((const float4*)x)[i];
    unsigned short* o = xb + (size_t)i * 4;
    o[0] = f2bf(v.x); o[1] = f2bf(v.y); o[2] = f2bf(v.z); o[3] = f2bf(v.w);
  }
}

// 4x W [1024][1024] f32 -> WT [1024][1024] bf16 (WT[n][k] = W[k][n]); z picks matrix
__global__ __launch_bounds__(256) void transpose_w4(
    const float* __restrict__ Wq, const float* __restrict__ Wk,
    const float* __restrict__ Wv, const float* __restrict__ Wp,
    unsigned short* __restrict__ wqkvT, unsigned short* __restrict__ wpT) {
  __shared__ float tile[32][33];
  const int zi = blockIdx.z;
  const float* src = (zi == 0) ? Wq : (zi == 1) ? Wk : (zi == 2) ? Wv : Wp;
  unsigned short* dst = (zi == 3) ? wpT : wqkvT + (size_t)zi * 1048576;
  const int bx = blockIdx.x * 32, by = blockIdx.y * 32;
  const int tx = threadIdx.x & 31, ty = threadIdx.x >> 5;  // 32 x 8
  #pragma unroll
  for (int i = 0; i < 32; i += 8)
    tile[ty + i][tx] = src[(size_t)(by + ty + i) * 1024 + bx + tx];
  __syncthreads();
  #pragma unroll
  for (int i = 0; i < 32; i += 8)
    dst[(size_t)(bx + ty + i) * 1024 + by + tx] = f2bf(tile[tx][ty + i]);
}

// ---------------- GEMM: C[M,N] = A[M,K] @ BT[N,K]^T ----------------
// bf16 path: cols < scale_cols get qscale (Q prescale); cols >= 2048 (V part)
// are written TRANSPOSED into vTo[col-2048][row] when vTo != null.
__global__ __launch_bounds__(256) void gemm_bt(
    const unsigned short* __restrict__ A, const unsigned short* __restrict__ BT,
    unsigned short* __restrict__ Cb, float* __restrict__ Cf,
    const float* __restrict__ bias, int M, int N, int K,
    float qscale, int scale_cols, unsigned short* __restrict__ vTo) {
  __shared__ unsigned short As[128 * 32];
  __shared__ unsigned short Bs[128 * 32];
  const int tid = threadIdx.x;
  const int lane = tid & 63, w = tid >> 6;
  const int wr = w >> 1, wc = w & 1;
  const int brow = blockIdx.y << 7, bcol = blockIdx.x << 7;

  f32x4 z = {0.f, 0.f, 0.f, 0.f};
  f32x4 acc[4][4];
  #pragma unroll
  for (int m = 0; m < 4; ++m)
    #pragma unroll
    for (int n = 0; n < 4; ++n) acc[m][n] = z;

  const int srow = tid >> 2;
  const int scol = (tid & 3) << 3;
  const unsigned short* Ap = A + (size_t)(brow + srow) * K + scol;
  const unsigned short* Bp = BT + (size_t)(bcol + srow) * K + scol;
  unsigned short* AsW = &As[w * 512];
  unsigned short* BsW = &Bs[w * 512];
  const size_t rowK64 = (size_t)64 * K;

  for (int k0 = 0; k0 < K; k0 += 32) {
    gload16(Ap + k0, AsW);
    gload16(Ap + rowK64 + k0, AsW + 2048);
    gload16(Bp + k0, BsW);
    gload16(Bp + rowK64 + k0, BsW + 2048);
    __syncthreads();
    shortx8 af[4], bf[4];
    const int koff = (lane >> 4) << 3;
    const int ar = (wr << 6) + (lane & 15);
    const int br = (wc << 6) + (lane & 15);
    #pragma unroll
    for (int m = 0; m < 4; ++m) af[m] = *(const shortx8*)&As[(ar + m * 16) * 32 + koff];
    #pragma unroll
    for (int n = 0; n < 4; ++n) bf[n] = *(const shortx8*)&Bs[(br + n * 16) * 32 + koff];
    #pragma unroll
    for (int m = 0; m < 4; ++m)
      #pragma unroll
      for (int n = 0; n < 4; ++n) acc[m][n] = MFMA16(af[m], bf[n], acc[m][n]);
    __syncthreads();
  }

  const int r0 = (lane >> 4) << 2;
  const int c0 = lane & 15;
  if (Cb) {
    if (vTo && bcol >= 2048) {
      #pragma unroll
      for (int m = 0; m < 4; ++m)
        #pragma unroll
        for (int n = 0; n < 4; ++n) {
          const int dp = bcol - 2048 + (wc << 6) + n * 16 + c0;
          const size_t rowb = brow + (wr << 6) + m * 16 + r0;
          shortx4 o4;
          #pragma unroll
          for (int j = 0; j < 4; ++j) o4[j] = (short)f2bf(acc[m][n][j]);
          *(shortx4*)&vTo[(size_t)dp * 4096 + rowb] = o4;
        }
    } else {
      #pragma unroll
      for (int m = 0; m < 4; ++m)
        #pragma unroll
        for (int n = 0; n < 4; ++n)
          #pragma unroll
          for (int j = 0; j < 4; ++j) {
            const size_t row = brow + (wr << 6) + m * 16 + r0 + j;
            const size_t col = bcol + (wc << 6) + n * 16 + c0;
            float v = acc[m][n][j];
            if ((int)col < scale_cols) v *= qscale;
            Cb[row * N + col] = f2bf(v);
          }
    }
  } else {
    #pragma unroll
    for (int m = 0; m < 4; ++m)
      #pragma unroll
      for (int n = 0; n < 4; ++n)
        #pragma unroll
        for (int j = 0; j < 4; ++j) {
          const size_t row = brow + (wr << 6) + m * 16 + r0 + j;
          const size_t col = bcol + (wc << 6) + n * 16 + c0;
          Cf[row * N + col] = acc[m][n][j] + bias[col];
        }
  }
}

// ---------------- flash attention v9 (kv-split, single-buffer LDS) ----------------
// Block = 2 INDEPENDENT warps over the same 32 q-rows; warp p does kv tiles
// t === p (mod 2), KVBLK=32. Single 8KB LDS buffer per warp (16KB/block ->
// all 8 queued blocks/CU resident). Per tile: vmcnt(0) -> ds_read all K/V
// frags -> lgkmcnt(0) -> restage same buffer for t+2 -> compute (~600cy)
// hides the L2 return. QK^T swapped at 32x32x16: lane owns q-col ql; softmax
// per-lane (15 fmax + 1 shfl). P relayout in-register (8 cvt_pk + 8
// shfl_xor(32)). O^T accum. End: warp1 dumps (m,l,O) to LDS; warp0 merges.

__global__ __launch_bounds__(128, 4) void attn_fwd(
    const unsigned short* __restrict__ qkv, const unsigned short* __restrict__ vT,
    unsigned short* __restrict__ att) {
  __shared__ unsigned short sh[2][4096];  // [warp][ K[32kv][64d] | V^T[64d][32kv] ]

  const int tid = threadIdx.x;
  const int lane = tid & 63;
  const int p = tid >> 6;                  // warp id = kv parity
  const int stream = blockIdx.x;           // (h,b)
  const int h = stream & 15, b = stream >> 4;
  const int qb = 63 - (int)blockIdx.y;     // 32-row q tile, descending work
  const int ql = lane & 31;
  const int hi = lane >> 5;
  const int q = qb * 32 + ql;

  // Q^T B-operand: qf[kc] = Q[q][16kc + 8hi + e], pre-scaled by SC_L2E
  shortx8 qf[4];
  {
    const unsigned short* qp = qkv + ((size_t)(b * 2048 + q)) * 3072 + h * 64 + 8 * hi;
    #pragma unroll
    for (int kc = 0; kc < 4; ++kc) qf[kc] = *(const shortx8*)(qp + 16 * kc);
  }

  f32x16 z16;
  #pragma unroll
  for (int i = 0; i < 16; ++i) z16[i] = 0.f;
  f32x16 accO0 = z16, accO1 = z16;  // O^T[d = 32dh + crow(r,hi)][q]
  float m_run = -__builtin_inff(), l_run = 0.f;

  // staging source bases (pre-swizzled): K row r -> chunk XOR S8(r), V -> S4(r)
  const unsigned short* kb[4];
  const unsigned short* vb[4];
  #pragma unroll
  for (int i = 0; i < 4; ++i) {
    const int krow = 8 * i + (lane >> 3);
    const int kcl = (lane & 7) ^ (((krow >> 1) ^ (krow >> 4)) & 7);
    kb[i] = qkv + ((size_t)(b * 2048 + krow)) * 3072 + 1024 + h * 64 + 8 * kcl;
    const int vrow = 16 * i + (lane >> 2);
    const int vcl = (lane & 3) ^ (((vrow >> 1) ^ (vrow >> 3)) & 3);
    vb[i] = vT + ((size_t)(h * 64 + vrow)) * 4096 + b * 2048 + 8 * vcl;
  }
  const int rs8 = ((ql >> 1) ^ (ql >> 4)) & 7;
  const int rs4 = ((ql >> 1) ^ (ql >> 3)) & 3;

  unsigned short* Kl = &sh[p][0];
  unsigned short* Vl = &sh[p][2048];

  #define STAGE(t_)                                                        \
    do {                                                                   \
      _Pragma("unroll")                                                    \
      for (int i = 0; i < 4; ++i) {                                        \
        gload16(kb[i] + (size_t)(t_) * 32 * 3072, Kl + i * 512);           \
        gload16(vb[i] + (t_) * 32, Vl + i * 512);                          \
      }                                                                    \
    } while (0)

  if (p <= qb) STAGE(p);
  for (int t = p; t <= qb; t += 2) {
    asm volatile("s_waitcnt vmcnt(0)" ::: "memory");  // tile t landed in LDS
    __builtin_amdgcn_sched_barrier(0);

    // read ALL K/V fragments for tile t (buffer dead afterwards)
    shortx8 kf[4];
    #pragma unroll
    for (int kc = 0; kc < 4; ++kc)
      kf[kc] = *(const shortx8*)&Kl[ql * 64 + 8 * ((2 * kc + hi) ^ rs8)];
    shortx8 vf[2][2];
    #pragma unroll
    for (int dh = 0; dh < 2; ++dh)
      #pragma unroll
      for (int ks = 0; ks < 2; ++ks)
        vf[dh][ks] = *(const shortx8*)&Vl[(32 * dh + ql) * 32 + 8 * ((2 * ks + hi) ^ rs4)];
    asm volatile("s_waitcnt lgkmcnt(0)" ::: "memory");  // frags in regs
    __builtin_amdgcn_sched_barrier(0);

    if (t + 2 <= qb) STAGE(t + 2);  // restage same buffer; compute hides return

    // QK^T: s = S^T[32kv][32q]
    __builtin_amdgcn_s_setprio(1);
    f32x16 s = z16;
    #pragma unroll
    for (int kc = 0; kc < 4; ++kc) s = MFMA32(kf[kc], qf[kc], s);
    __builtin_amdgcn_s_setprio(0);

    // causal mask on diagonal tile: kv_local = (r&3)+8(r>>2)+4hi, qrel = ql
    if (t == qb) {
      #pragma unroll
      for (int r = 0; r < 16; ++r) {
        const int kvl = (r & 3) + 8 * (r >> 2) + 4 * hi;
        if (kvl > ql) s[r] = -__builtin_inff();
      }
    }

    // per-lane softmax over 16 regs + partner shfl
    float m8[8], m4[4];
    #pragma unroll
    for (int i = 0; i < 8; ++i) m8[i] = fmaxf(s[2 * i], s[2 * i + 1]);
    #pragma unroll
    for (int i = 0; i < 4; ++i) m4[i] = fmaxf(m8[2 * i], m8[2 * i + 1]);
    float mx = fmaxf(fmaxf(m4[0], m4[1]), fmaxf(m4[2], m4[3]));
    mx = fmaxf(mx, __shfl_xor(mx, 32));

    if (!__all(mx <= m_run + 8.0f)) {  // defer-max (THR=8 in log2)
      const float nm = fmaxf(m_run, mx);
      const float alpha = fexp2(m_run - nm);
      l_run *= alpha;
      #pragma unroll
      for (int r = 0; r < 16; ++r) { accO0[r] *= alpha; accO1[r] *= alpha; }
      m_run = nm;
    }

    #pragma unroll
    for (int r = 0; r < 16; ++r) s[r] = fexp2(s[r] - m_run);
    float a8[8], a4[4];
    #pragma unroll
    for (int i = 0; i < 8; ++i) a8[i] = s[2 * i] + s[2 * i + 1];
    #pragma unroll
    for (int i = 0; i < 4; ++i) a4[i] = a8[2 * i] + a8[2 * i + 1];
    float rsum = (a4[0] + a4[1]) + (a4[2] + a4[3]);
    rsum += __shfl_xor(rsum, 32);
    l_run += rsum;

    // pack P + in-register exchange + PV
    unsigned wv[8], xv[8];
    #pragma unroll
    for (int i = 0; i < 8; ++i)
      asm("v_cvt_pk_bf16_f32 %0, %1, %2" : "=v"(wv[i]) : "v"(s[2 * i]), "v"(s[2 * i + 1]));
    #pragma unroll
    for (int i = 0; i < 8; ++i) xv[i] = __shfl_xor(wv[i], 32);
    __builtin_amdgcn_s_setprio(1);
    #pragma unroll
    for (int ss = 0; ss < 2; ++ss) {
      union { unsigned u[4]; shortx8 s8; } pb;
      pb.u[0] = hi ? xv[4 * ss + 2] : wv[4 * ss];
      pb.u[1] = hi ? xv[4 * ss + 3] : wv[4 * ss + 1];
      pb.u[2] = hi ? wv[4 * ss + 2] : xv[4 * ss];
      pb.u[3] = hi ? wv[4 * ss + 3] : xv[4 * ss + 1];
      accO0 = MFMA32(vf[0][ss], pb.s8, accO0);
      accO1 = MFMA32(vf[1][ss], pb.s8, accO1);
    }
    __builtin_amdgcn_s_setprio(0);
  }
  #undef STAGE

  // ---- merge the two kv-partial states ----
  __syncthreads();
  float* mb = (float*)&sh[0][0];   // 8 KB: [reg-group 8][lane 64][4 f32]
  float* ml = mb + 2048;           // 512 B: m[64], l[64]
  if (p == 1) {
    #pragma unroll
    for (int rg = 0; rg < 4; ++rg) {
      f32x4 v0 = {accO0[4 * rg], accO0[4 * rg + 1], accO0[4 * rg + 2], accO0[4 * rg + 3]};
      f32x4 v1 = {accO1[4 * rg], accO1[4 * rg + 1], accO1[4 * rg + 2], accO1[4 * rg + 3]};
      *(f32x4*)&mb[(rg * 64 + lane) * 4] = v0;
      *(f32x4*)&mb[((4 + rg) * 64 + lane) * 4] = v1;
    }
    ml[lane] = m_run;
    ml[64 + lane] = l_run;
  }
  __syncthreads();
  if (p == 0) {
    const float m1 = ml[lane], l1 = ml[64 + lane];
    const float mf = fmaxf(m_run, m1);
    const float a0 = fexp2(m_run - mf);
    const float a1 = fexp2(m1 - mf);
    const float inv = 1.f / (l_run * a0 + l1 * a1);
    unsigned short* op = att + ((size_t)(b * 2048 + q)) * 1024 + h * 64;
    #pragma unroll
    for (int rq = 0; rq < 4; ++rq) {
      f32x4 p0 = *(const f32x4*)&mb[(rq * 64 + lane) * 4];
      f32x4 p1 = *(const f32x4*)&mb[((4 + rq) * 64 + lane) * 4];
      shortx4 o0, o1;
      #pragma unroll
      for (int j = 0; j < 4; ++j) {
        o0[j] = (short)f2bf((accO0[4 * rq + j] * a0 + p0[j] * a1) * inv);
        o1[j] = (short)f2bf((accO1[4 * rq + j] * a0 + p1[j] * a1) * inv);
      }
      *(shortx4*)&op[8 * rq + 4 * hi] = o0;
      *(shortx4*)&op[32 + 8 * rq + 4 * hi] = o1;
    }
  }
}

// ---------------- launch ----------------
extern "C" void kernel_launch(void* const* d_in, const int* in_sizes, int n_in,
                              void* d_out, int out_size, void* d_ws, size_t ws_size,
                              hipStream_t stream) {
  const float* x  = (const float*)d_in[0];
  const float* Wq = (const float*)d_in[1];
  const float* Wk = (const float*)d_in[2];
  const float* Wv = (const float*)d_in[3];
  const float* Wp = (const float*)d_in[4];
  const float* bp = (const float*)d_in[5];

  char* ws = (char*)d_ws;
  unsigned short* xb    = (unsigned short*)(ws);                        //  8 MB [4096][1024]
  unsigned short* wqkvT = (unsigned short*)(ws + (size_t)8  * 1048576); //  6 MB [3072][1024]
  unsigned short* wpT   = (unsigned short*)(ws + (size_t)14 * 1048576); //  2 MB [1024][1024]
  unsigned short* qkv   = (unsigned short*)(ws + (size_t)16 * 1048576); // 24 MB [4096][3072]
  unsigned short* vT    = (unsigned short*)(ws + (size_t)40 * 1048576); //  8 MB [1024][4096]
  unsigned short* att   = (unsigned short*)(ws + (size_t)48 * 1048576); //  8 MB [4096][1024]

  cvt_x<<<dim3(4096), dim3(256), 0, stream>>>(x, xb, 1048576);
  transpose_w4<<<dim3(32, 32, 4), dim3(256), 0, stream>>>(Wq, Wk, Wv, Wp, wqkvT, wpT);
  gemm_bt<<<dim3(24, 32), dim3(256), 0, stream>>>(xb, wqkvT, qkv, nullptr, nullptr,
                                                  4096, 3072, 1024, SC_L2E, 1024, vT);
  attn_fwd<<<dim3(32, 64), dim3(128), 0, stream>>>(qkv, vT, att);
  gemm_bt<<<dim3(8, 32), dim3(256), 0, stream>>>(att, wpT, nullptr, (float*)d_out, bp,
                                                 4096, 1024, 1024, 0.f, 0, nullptr);
}